// Round 1
// baseline (105.865 us; speedup 1.0000x reference)
//
#include <hip/hip_runtime.h>
#include <hip/hip_bf16.h>

#define NROWS 12288
#define DDIM  128
#define NT    96      // 12288/128 tiles per dimension
#define CHUNK 4       // j-tiles per block
#define NBLK  1200    // sum over bands of ceil((96-bi)/4)

typedef __bf16 bf16x8 __attribute__((ext_vector_type(8)));
typedef float  f32x4  __attribute__((ext_vector_type(4)));

// async global->LDS, 16B per lane; LDS dst is wave-uniform base + lane*16
#define GLD_LDS(g, l) __builtin_amdgcn_global_load_lds(                      \
    (const __attribute__((address_space(1))) void*)(g),                      \
    (__attribute__((address_space(3))) void*)(l), 16, 0, 0)

__device__ __forceinline__ unsigned short f2bf(float f) {
    union { float f; unsigned u; } a; a.f = f;
    unsigned r = a.u + 0x7fffu + ((a.u >> 16) & 1u);   // RNE to bf16
    return (unsigned short)(r >> 16);
}

__global__ void convert_kernel(const float* __restrict__ x, unsigned short* __restrict__ xb,
                               float* __restrict__ rowsum, float* __restrict__ out) {
    int gid = blockIdx.x * 256 + threadIdx.x;
    int i = gid * 4;
    float4 v = *(const float4*)(x + i);
    ushort4 o;
    o.x = f2bf(v.x); o.y = f2bf(v.y); o.z = f2bf(v.z); o.w = f2bf(v.w);
    *(ushort4*)(xb + i) = o;
    if (gid < NROWS) rowsum[gid] = 0.f;
    if (gid == 0) out[0] = 0.f;
}

// Stage one 128x128 bf16 tile into LDS via global_load_lds, XOR-swizzled:
// LDS slot (row, s) holds global 16B-chunk (s ^ (row&7)) of row.
__device__ __forceinline__ void stage_tile(const unsigned short* __restrict__ xb,
                                           int row0, unsigned short* lds,
                                           int wave, int lane) {
    #pragma unroll
    for (int it = 0; it < 8; ++it) {
        int rbase = wave * 32 + it * 4;               // wave-uniform
        int r = rbase + (lane >> 4);
        int chunk = (lane & 15) ^ (r & 7);
        GLD_LDS(xb + (size_t)(row0 + r) * DDIM + chunk * 8, lds + rbase * DDIM);
    }
}

// One block per chunk of up-to-4 upper-triangular 128x128 tiles sharing a row band.
// A-fragments register-resident across the strip; B tiles double-buffered in LDS
// (A's LDS space is reused as the second B buffer once fragments are extracted):
// prefetch tile t+1 is issued BEFORE computing tile t -> one barrier per tile,
// DMA latency hidden under MFMA + exp epilogue.
__global__ __launch_bounds__(256, 2) void gemm_exp_rowsum(
    const unsigned short* __restrict__ xb, float* __restrict__ rowsum)
{
    __shared__ __align__(16) unsigned short As[128 * DDIM];  // buf0: A, then B double-buffer
    __shared__ __align__(16) unsigned short Bs[128 * DDIM];  // buf1
    __shared__ float csumS[CHUNK * 128];
    __shared__ float rsum[128];

    const int tid = threadIdx.x;

    // decode blockIdx -> (band bi, chunk start jt0)
    int rem = blockIdx.x, bi = 0;
    for (;;) {
        int nch = (NT - bi + CHUNK - 1) / CHUNK;
        if (rem < nch) break;
        rem -= nch; ++bi;
    }
    const int jt0 = bi + rem * CHUNK;
    const int ntiles = min(CHUNK, NT - jt0);
    const int i0 = bi * 128;

    for (int k = tid; k < CHUNK * 128; k += 256) csumS[k] = 0.f;
    if (tid < 128) rsum[tid] = 0.f;

    const int wave = tid >> 6, lane = tid & 63;
    const int wm = wave >> 1, wn = wave & 1;      // 2x2 waves, 64x64 each
    const int m16 = lane & 15, q = lane >> 4;

    stage_tile(xb, i0, As, wave, lane);           // A tile DMA
    stage_tile(xb, jt0 * 128, Bs, wave, lane);    // first B tile DMA (both in flight)
    __syncthreads();   // both DMAs complete (vmcnt drained) + csum/rsum zeroed

    // A fragments: row = wm*64+mi*16+m16, k-chunk = ks*4+q (swizzled). Stay in VGPRs.
    bf16x8 af[4][4];
    #pragma unroll
    for (int mi = 0; mi < 4; ++mi) {
        int r = wm * 64 + mi * 16 + m16;
        #pragma unroll
        for (int ks = 0; ks < 4; ++ks)
            af[mi][ks] = *(const bf16x8*)(&As[r * DDIM + (((ks * 4 + q) ^ (r & 7)) * 8)]);
    }
    __syncthreads();   // all waves done reading As -> safe to reuse as B buffer

    // exp(s/T) == exp2(s * invT*log2e)
    const float SCALE = 20.609929155556625f;      // (1/0.07) * log2(e)

    f32x4 rp4[4];
    #pragma unroll
    for (int mi = 0; mi < 4; ++mi) rp4[mi] = (f32x4){0.f, 0.f, 0.f, 0.f};

    unsigned short* curB = Bs;
    unsigned short* nxtB = As;

    for (int t = 0; t < ntiles; ++t) {
        const int jt = jt0 + t;

        // issue next tile's DMA before touching current tile (overlaps with compute)
        if (t + 1 < ntiles) stage_tile(xb, (jt + 1) * 128, nxtB, wave, lane);

        f32x4 acc[4][4] = {};
        #pragma unroll
        for (int ks = 0; ks < 4; ++ks) {
            bf16x8 bfr[4];
            #pragma unroll
            for (int ni = 0; ni < 4; ++ni) {
                int r = wn * 64 + ni * 16 + m16;
                bfr[ni] = *(const bf16x8*)(&curB[r * DDIM + (((ks * 4 + q) ^ (r & 7)) * 8)]);
            }
            __builtin_amdgcn_s_setprio(1);
            #pragma unroll
            for (int mi = 0; mi < 4; ++mi)
                #pragma unroll
                for (int ni = 0; ni < 4; ++ni)
                    acc[mi][ni] = __builtin_amdgcn_mfma_f32_16x16x32_bf16(
                        af[mi][ks], bfr[ni], acc[mi][ni], 0, 0, 0);
            __builtin_amdgcn_s_setprio(0);
        }

        // C/D: col = m16, row = q*4 + r  [verified in prior session]
        // vectorized epilogue: v_pk_mul + v_exp + v_pk_add
        f32x4 cp4[4];
        #pragma unroll
        for (int ni = 0; ni < 4; ++ni) cp4[ni] = (f32x4){0.f, 0.f, 0.f, 0.f};

        #pragma unroll
        for (int mi = 0; mi < 4; ++mi)
            #pragma unroll
            for (int ni = 0; ni < 4; ++ni) {
                f32x4 sv = acc[mi][ni] * SCALE;
                f32x4 ev;
                ev[0] = __builtin_amdgcn_exp2f(sv[0]);
                ev[1] = __builtin_amdgcn_exp2f(sv[1]);
                ev[2] = __builtin_amdgcn_exp2f(sv[2]);
                ev[3] = __builtin_amdgcn_exp2f(sv[3]);
                rp4[mi] += ev;                 // row partials (register, whole strip)
                cp4[ni] += ev;                 // col partials (this tile)
            }

        if (jt != bi) {                        // diagonal tile: rows == cols, no double count
            #pragma unroll
            for (int ni = 0; ni < 4; ++ni) {
                float s = (cp4[ni][0] + cp4[ni][1]) + (cp4[ni][2] + cp4[ni][3]);
                s += __shfl_xor(s, 16);
                s += __shfl_xor(s, 32);
                if (q == 0) atomicAdd(&csumS[t * 128 + wn * 64 + ni * 16 + m16], s);
            }
        }

        __syncthreads();   // prefetch DMA landed (vmcnt drain) + all reads of curB done
        unsigned short* tmp = curB; curB = nxtB; nxtB = tmp;
    }

    // row reduction: once per block
    #pragma unroll
    for (int mi = 0; mi < 4; ++mi)
        #pragma unroll
        for (int r = 0; r < 4; ++r) {
            float s = rp4[mi][r];
            s += __shfl_xor(s, 1);
            s += __shfl_xor(s, 2);
            s += __shfl_xor(s, 4);
            s += __shfl_xor(s, 8);
            if (m16 == 0) atomicAdd(&rsum[wm * 64 + mi * 16 + q * 4 + r], s);
        }
    __syncthreads();

    if (tid < 128) atomicAdd(&rowsum[i0 + tid], rsum[tid]);
    for (int k = tid; k < ntiles * 128; k += 256) {
        float v = csumS[k];
        if (v != 0.f) atomicAdd(&rowsum[jt0 * 128 + k], v);
    }
}

__global__ void finalize_kernel(const float* __restrict__ rowsum, float* __restrict__ out) {
    __shared__ float red[4];
    int gid = blockIdx.x * 256 + threadIdx.x;
    float lg = __logf(rowsum[gid]);
    #pragma unroll
    for (int off = 1; off < 64; off <<= 1)
        lg += __shfl_xor(lg, off);
    const int wv = threadIdx.x >> 6, ln = threadIdx.x & 63;
    if (ln == 0) red[wv] = lg;
    __syncthreads();
    if (threadIdx.x == 0)
        atomicAdd(out, (red[0] + red[1] + red[2] + red[3]) * (1.0f / (float)NROWS));
}

extern "C" void kernel_launch(void* const* d_in, const int* in_sizes, int n_in,
                              void* d_out, int out_size, void* d_ws, size_t ws_size,
                              hipStream_t stream) {
    const float* x = (const float*)d_in[0];
    float* out = (float*)d_out;

    float* rowsum = (float*)d_ws;                                                 // 48 KB
    unsigned short* xb = (unsigned short*)((char*)d_ws + NROWS * sizeof(float));  // 3 MB bf16

    convert_kernel<<<dim3((NROWS * DDIM) / (4 * 256)), dim3(256), 0, stream>>>(x, xb, rowsum, out);
    gemm_exp_rowsum<<<dim3(NBLK), dim3(256), 0, stream>>>(xb, rowsum);
    finalize_kernel<<<dim3(NROWS / 256), dim3(256), 0, stream>>>(rowsum, out);
}

// Round 2
// 104.352 us; speedup vs baseline: 1.0145x; 1.0145x over previous
//
#include <hip/hip_runtime.h>
#include <hip/hip_bf16.h>

#define NROWS 12288
#define DDIM  128
#define NT    96      // 12288/128 tiles per dimension
#define CHUNK 6       // j-tiles per block
#define NBLK  816     // sum over bi of ceil((96-bi)/6)  -> single co-resident wave of blocks

typedef __bf16 bf16x8 __attribute__((ext_vector_type(8)));
typedef float  f32x4  __attribute__((ext_vector_type(4)));

// async global->LDS, 16B per lane; LDS dst is wave-uniform base + lane*16
#define GLD_LDS(g, l) __builtin_amdgcn_global_load_lds(                      \
    (const __attribute__((address_space(1))) void*)(g),                      \
    (__attribute__((address_space(3))) void*)(l), 16, 0, 0)

__device__ __forceinline__ unsigned short f2bf(float f) {
    union { float f; unsigned u; } a; a.f = f;
    unsigned r = a.u + 0x7fffu + ((a.u >> 16) & 1u);   // RNE to bf16
    return (unsigned short)(r >> 16);
}

__global__ void convert_kernel(const float* __restrict__ x, unsigned short* __restrict__ xb,
                               float* __restrict__ rowsum, float* __restrict__ out) {
    int gid = blockIdx.x * 256 + threadIdx.x;
    int i = gid * 4;
    float4 v = *(const float4*)(x + i);
    ushort4 o;
    o.x = f2bf(v.x); o.y = f2bf(v.y); o.z = f2bf(v.z); o.w = f2bf(v.w);
    *(ushort4*)(xb + i) = o;
    if (gid < NROWS) rowsum[gid] = 0.f;
    if (gid == 0) out[0] = 0.f;
}

// 35KB-LDS variant: A staged once (32KB area), then that area is reused as TWO
// 16KB 64-row B half-tile buffers (double-buffered, prefetch one phase ahead).
// 4 blocks/CU (16 waves) instead of 2 (8 waves) -> 2x latency hiding; and the
// whole 816-block grid is co-resident (single scheduling round).
__global__ __launch_bounds__(256, 4) void gemm_exp_rowsum(
    const unsigned short* __restrict__ xb, float* __restrict__ rowsum)
{
    __shared__ __align__(16) unsigned short smem[128 * DDIM];  // 32KB: A-stage, then B halves
    __shared__ float csumS[CHUNK * 128];                       // 3KB col partials

    const int tid = threadIdx.x;

    // decode blockIdx -> (band bi, chunk start jt0)
    int rem = blockIdx.x, bi = 0;
    for (;;) {
        int nch = (NT - bi + CHUNK - 1) / CHUNK;
        if (rem < nch) break;
        rem -= nch; ++bi;
    }
    const int jt0 = bi + rem * CHUNK;
    const int ntiles = min(CHUNK, NT - jt0);
    const int H = 2 * ntiles;                    // 64-col phases
    const int i0 = bi * 128;

    for (int k = tid; k < CHUNK * 128; k += 256) csumS[k] = 0.f;

    const int wave = tid >> 6, lane = tid & 63;
    const int m16 = lane & 15, q = lane >> 4;

    // ---- stage full 128x128 A tile, XOR-swizzled: slot s of row r holds chunk s^(r&7)
    #pragma unroll
    for (int it = 0; it < 8; ++it) {
        int rbase = wave * 32 + it * 4;          // wave-uniform
        int r = rbase + (lane >> 4);
        int chunk = (lane & 15) ^ (r & 7);
        GLD_LDS(xb + (size_t)(i0 + r) * DDIM + chunk * 8, smem + rbase * DDIM);
    }
    __syncthreads();   // A DMA drained + csum zeroed

    // A fragments: wave owns rows wave*32 + mi*16 + m16 (mi in 0..1). 32 VGPR.
    bf16x8 af[2][4];
    #pragma unroll
    for (int mi = 0; mi < 2; ++mi) {
        int r = wave * 32 + mi * 16 + m16;
        #pragma unroll
        for (int ks = 0; ks < 4; ++ks)
            af[mi][ks] = *(const bf16x8*)(&smem[r * DDIM + (((ks * 4 + q) ^ (r & 7)) * 8)]);
    }
    __syncthreads();   // all waves done reading A area -> safe to reuse for B halves

    unsigned short* const buf0 = smem;
    unsigned short* const buf1 = smem + 64 * DDIM;

    // stage one 64-row B half (16KB), 4 DMA insts per wave
    #define STAGE_HALF(h, dst) do {                                              \
        int jrow0_ = jt0 * 128 + (h) * 64;                                       \
        _Pragma("unroll")                                                        \
        for (int it = 0; it < 4; ++it) {                                         \
            int rbase = wave * 16 + it * 4;                                      \
            int r = rbase + (lane >> 4);                                         \
            int chunk = (lane & 15) ^ (r & 7);                                   \
            GLD_LDS(xb + (size_t)(jrow0_ + r) * DDIM + chunk * 8, (dst) + rbase * DDIM); \
        }                                                                        \
    } while (0)

    STAGE_HALF(0, buf0);

    // exp(s/T) == exp2(s * invT*log2e)
    const float SCALE = 20.609929155556625f;     // (1/0.07) * log2(e)

    f32x4 rp4[2];
    rp4[0] = (f32x4){0.f, 0.f, 0.f, 0.f};
    rp4[1] = (f32x4){0.f, 0.f, 0.f, 0.f};

    for (int h = 0; h < H; ++h) {
        __syncthreads();   // buf[h&1] staged (vmcnt drained) + prior reads of other buf done
        unsigned short* nxt = ((h + 1) & 1) ? buf1 : buf0;
        if (h + 1 < H) STAGE_HALF(h + 1, nxt);   // hidden under this phase's compute

        const unsigned short* cb = (h & 1) ? buf1 : buf0;

        f32x4 acc[2][4] = {};
        #pragma unroll
        for (int ks = 0; ks < 4; ++ks) {
            bf16x8 bfr[4];
            #pragma unroll
            for (int ni = 0; ni < 4; ++ni) {
                int r = ni * 16 + m16;           // B-half row = output col (local)
                bfr[ni] = *(const bf16x8*)(&cb[r * DDIM + (((ks * 4 + q) ^ (r & 7)) * 8)]);
            }
            __builtin_amdgcn_s_setprio(1);
            #pragma unroll
            for (int mi = 0; mi < 2; ++mi)
                #pragma unroll
                for (int ni = 0; ni < 4; ++ni)
                    acc[mi][ni] = __builtin_amdgcn_mfma_f32_16x16x32_bf16(
                        af[mi][ks], bfr[ni], acc[mi][ni], 0, 0, 0);
            __builtin_amdgcn_s_setprio(0);
        }

        // C/D layout: col = m16, row = q*4 + r  [verified earlier, absmax=0]
        float cp[4] = {0.f, 0.f, 0.f, 0.f};
        #pragma unroll
        for (int mi = 0; mi < 2; ++mi)
            #pragma unroll
            for (int ni = 0; ni < 4; ++ni) {
                f32x4 sv = acc[mi][ni] * SCALE;
                f32x4 ev;
                ev[0] = __builtin_amdgcn_exp2f(sv[0]);
                ev[1] = __builtin_amdgcn_exp2f(sv[1]);
                ev[2] = __builtin_amdgcn_exp2f(sv[2]);
                ev[3] = __builtin_amdgcn_exp2f(sv[3]);
                rp4[mi] += ev;                                   // row partials (whole strip)
                cp[ni] += (ev[0] + ev[1]) + (ev[2] + ev[3]);     // col partials (this phase)
            }

        if (jt0 + (h >> 1) != bi) {              // diagonal tile: skip col side (no double count)
            #pragma unroll
            for (int ni = 0; ni < 4; ++ni) {
                float s = cp[ni];
                s += __shfl_xor(s, 16);
                s += __shfl_xor(s, 32);
                if (q == 0) atomicAdd(&csumS[h * 64 + ni * 16 + m16], s);
            }
        }
    }

    // row totals: row = wave*32 + mi*16 + q*4 + r; reduce over the 16 m16-lanes
    #pragma unroll
    for (int mi = 0; mi < 2; ++mi)
        #pragma unroll
        for (int r = 0; r < 4; ++r) {
            float s = rp4[mi][r];
            s += __shfl_xor(s, 1);
            s += __shfl_xor(s, 2);
            s += __shfl_xor(s, 4);
            s += __shfl_xor(s, 8);
            if (m16 == 0) atomicAdd(&rowsum[i0 + wave * 32 + mi * 16 + q * 4 + r], s);
        }

    __syncthreads();   // all csum LDS atomics done
    for (int k = tid; k < ntiles * 128; k += 256) {
        float v = csumS[k];
        if (v != 0.f) atomicAdd(&rowsum[jt0 * 128 + k], v);
    }
}

__global__ void finalize_kernel(const float* __restrict__ rowsum, float* __restrict__ out) {
    __shared__ float red[4];
    int gid = blockIdx.x * 256 + threadIdx.x;
    float lg = __logf(rowsum[gid]);
    #pragma unroll
    for (int off = 1; off < 64; off <<= 1)
        lg += __shfl_xor(lg, off);
    const int wv = threadIdx.x >> 6, ln = threadIdx.x & 63;
    if (ln == 0) red[wv] = lg;
    __syncthreads();
    if (threadIdx.x == 0)
        atomicAdd(out, (red[0] + red[1] + red[2] + red[3]) * (1.0f / (float)NROWS));
}

extern "C" void kernel_launch(void* const* d_in, const int* in_sizes, int n_in,
                              void* d_out, int out_size, void* d_ws, size_t ws_size,
                              hipStream_t stream) {
    const float* x = (const float*)d_in[0];
    float* out = (float*)d_out;

    float* rowsum = (float*)d_ws;                                                 // 48 KB
    unsigned short* xb = (unsigned short*)((char*)d_ws + NROWS * sizeof(float));  // 3 MB bf16

    convert_kernel<<<dim3((NROWS * DDIM) / (4 * 256)), dim3(256), 0, stream>>>(x, xb, rowsum, out);
    gemm_exp_rowsum<<<dim3(NBLK), dim3(256), 0, stream>>>(xb, rowsum);
    finalize_kernel<<<dim3(NROWS / 256), dim3(256), 0, stream>>>(rowsum, out);
}

// Round 6
// 104.140 us; speedup vs baseline: 1.0166x; 1.0020x over previous
//
#include <hip/hip_runtime.h>
#include <hip/hip_bf16.h>

#define NROWS 12288
#define DDIM  128
#define NT    96      // 12288/128 tiles per dimension
#define CHUNK 6       // j-tiles per block
#define NBLK  816     // sum over bi of ceil((96-bi)/6) -> single co-resident round

typedef __bf16 bf16x8 __attribute__((ext_vector_type(8)));
typedef float  f32x4  __attribute__((ext_vector_type(4)));

// async global->LDS, 16B per lane; LDS dst is wave-uniform base + lane*16
#define GLD_LDS(g, l) __builtin_amdgcn_global_load_lds(                      \
    (const __attribute__((address_space(1))) void*)(g),                      \
    (__attribute__((address_space(3))) void*)(l), 16, 0, 0)

__device__ __forceinline__ unsigned short f2bf(float f) {
    union { float f; unsigned u; } a; a.f = f;
    unsigned r = a.u + 0x7fffu + ((a.u >> 16) & 1u);   // RNE to bf16
    return (unsigned short)(r >> 16);
}

__global__ void convert_kernel(const float* __restrict__ x, unsigned short* __restrict__ xb,
                               float* __restrict__ rowsum, float* __restrict__ out) {
    int gid = blockIdx.x * 256 + threadIdx.x;
    int i = gid * 4;
    float4 v = *(const float4*)(x + i);
    ushort4 o;
    o.x = f2bf(v.x); o.y = f2bf(v.y); o.z = f2bf(v.z); o.w = f2bf(v.w);
    *(ushort4*)(xb + i) = o;
    if (gid < NROWS) rowsum[gid] = 0.f;
    if (gid == 0) out[0] = 0.f;
}

// Counted-vmcnt pipelined variant (T3+T4): raw s_barrier, never drain vmcnt to 0
// in the main loop. A staged once (32KB), area reused as two 16KB 64-row B
// half-buffers; phase h+1's stage DMAs stay in flight across phase h's barriers.
__global__ __launch_bounds__(256, 4) void gemm_exp_rowsum(
    const unsigned short* __restrict__ xb, float* __restrict__ rowsum)
{
    __shared__ __align__(16) unsigned short smem[128 * DDIM];  // 32KB: A, then 2x16KB B halves
    __shared__ float csumS[CHUNK * 128];                       // 3KB col partials

    const int tid = threadIdx.x;

    // decode blockIdx -> (band bi, chunk start jt0)
    int rem = blockIdx.x, bi = 0;
    for (;;) {
        int nch = (NT - bi + CHUNK - 1) / CHUNK;
        if (rem < nch) break;
        rem -= nch; ++bi;
    }
    const int jt0 = bi + rem * CHUNK;
    const int ntiles = min(CHUNK, NT - jt0);
    const int H = 2 * ntiles;                    // 64-col phases (>= 2)
    const int i0 = bi * 128;

    for (int k = tid; k < CHUNK * 128; k += 256) csumS[k] = 0.f;

    const int wave = tid >> 6, lane = tid & 63;
    const int m16 = lane & 15, q = lane >> 4;

    // ---- stage full 128x128 A tile, XOR-swizzled: LDS slot s of row r = global chunk s^(r&7)
    #pragma unroll
    for (int it = 0; it < 8; ++it) {
        int rbase = wave * 32 + it * 4;          // wave-uniform
        int r = rbase + (lane >> 4);
        int chunk = (lane & 15) ^ (r & 7);
        GLD_LDS(xb + (size_t)(i0 + r) * DDIM + chunk * 8, smem + rbase * DDIM);
    }
    asm volatile("s_waitcnt vmcnt(0)" ::: "memory");   // A DMA done
    __builtin_amdgcn_s_barrier();

    // A fragments: wave owns rows wave*32 + mi*16 + m16 (mi in 0..1)
    bf16x8 af[2][4];
    #pragma unroll
    for (int mi = 0; mi < 2; ++mi) {
        int r = wave * 32 + mi * 16 + m16;
        #pragma unroll
        for (int ks = 0; ks < 4; ++ks)
            af[mi][ks] = *(const bf16x8*)(&smem[r * DDIM + (((ks * 4 + q) ^ (r & 7)) * 8)]);
    }
    asm volatile("s_waitcnt lgkmcnt(0)" ::: "memory"); // af in regs before A area is overwritten
    __builtin_amdgcn_sched_barrier(0);
    __builtin_amdgcn_s_barrier();                      // all waves done reading A area

    // stage one 64-row B half (16KB): exactly 4 DMA insts per wave (vmcnt counts rely on this)
    #define STAGE_HALF(h) do {                                                   \
        unsigned short* dst_ = smem + ((h) & 1) * (64 * DDIM);                   \
        int jrow0_ = jt0 * 128 + (h) * 64;                                       \
        _Pragma("unroll")                                                        \
        for (int it = 0; it < 4; ++it) {                                         \
            int rbase = wave * 16 + it * 4;                                      \
            int r = rbase + (lane >> 4);                                         \
            int chunk = (lane & 15) ^ (r & 7);                                   \
            GLD_LDS(xb + (size_t)(jrow0_ + r) * DDIM + chunk * 8, dst_ + rbase * DDIM); \
        }                                                                        \
    } while (0)

    STAGE_HALF(0);
    STAGE_HALF(1);                               // depth-2 pipeline primed (8 DMAs in flight)

    // exp(s/T) == exp2(s * invT*log2e)
    const float SCALE = 20.609929155556625f;     // (1/0.07) * log2(e)

    f32x4 rp4[2];
    rp4[0] = (f32x4){0.f, 0.f, 0.f, 0.f};
    rp4[1] = (f32x4){0.f, 0.f, 0.f, 0.f};

    for (int h = 0; h < H; ++h) {
        // wait for THIS phase's 4 DMAs only; next phase's 4 stay in flight
        if (h + 1 < H) asm volatile("s_waitcnt vmcnt(4)" ::: "memory");
        else           asm volatile("s_waitcnt vmcnt(0)" ::: "memory");
        __builtin_amdgcn_s_barrier();            // raw: no compiler-forced full drain

        const unsigned short* cb = smem + (h & 1) * (64 * DDIM);

        f32x4 acc[2][4] = {};
        #pragma unroll
        for (int ks = 0; ks < 4; ++ks) {
            bf16x8 bfr[4];
            #pragma unroll
            for (int ni = 0; ni < 4; ++ni) {
                int r = ni * 16 + m16;           // B-half row = output col (local)
                bfr[ni] = *(const bf16x8*)(&cb[r * DDIM + (((ks * 4 + q) ^ (r & 7)) * 8)]);
            }
            __builtin_amdgcn_s_setprio(1);
            #pragma unroll
            for (int mi = 0; mi < 2; ++mi)
                #pragma unroll
                for (int ni = 0; ni < 4; ++ni)
                    acc[mi][ni] = __builtin_amdgcn_mfma_f32_16x16x32_bf16(
                        af[mi][ks], bfr[ni], acc[mi][ni], 0, 0, 0);
            __builtin_amdgcn_s_setprio(0);
        }

        // C/D layout: col = m16, row = q*4 + r  [verified, absmax=0]
        f32x4 cp4[4];
        #pragma unroll
        for (int ni = 0; ni < 4; ++ni) cp4[ni] = (f32x4){0.f, 0.f, 0.f, 0.f};

        #pragma unroll
        for (int mi = 0; mi < 2; ++mi)
            #pragma unroll
            for (int ni = 0; ni < 4; ++ni) {
                f32x4 sv = acc[mi][ni] * SCALE;
                f32x4 ev;
                ev[0] = __builtin_amdgcn_exp2f(sv[0]);
                ev[1] = __builtin_amdgcn_exp2f(sv[1]);
                ev[2] = __builtin_amdgcn_exp2f(sv[2]);
                ev[3] = __builtin_amdgcn_exp2f(sv[3]);
                rp4[mi] += ev;                   // row partials (register, whole strip)
                cp4[ni] += ev;                   // col partials (this phase)
            }

        if (jt0 + (h >> 1) != bi) {              // diagonal tile: skip col side (no double count)
            #pragma unroll
            for (int ni = 0; ni < 4; ++ni) {
                float s = (cp4[ni][0] + cp4[ni][1]) + (cp4[ni][2] + cp4[ni][3]);
                s += __shfl_xor(s, 16);
                s += __shfl_xor(s, 32);
                if (q == 0) atomicAdd(&csumS[h * 64 + ni * 16 + m16], s);
            }
        }

        __builtin_amdgcn_s_barrier();            // all waves done reading cb
        __builtin_amdgcn_sched_barrier(0);       // keep restage below the barrier
        if (h + 2 < H) STAGE_HALF(h + 2);        // overwrite the buffer just freed
    }

    // row totals: row = wave*32 + mi*16 + q*4 + r; reduce over the 16 m16-lanes
    #pragma unroll
    for (int mi = 0; mi < 2; ++mi)
        #pragma unroll
        for (int r = 0; r < 4; ++r) {
            float s = rp4[mi][r];
            s += __shfl_xor(s, 1);
            s += __shfl_xor(s, 2);
            s += __shfl_xor(s, 4);
            s += __shfl_xor(s, 8);
            if (m16 == 0) atomicAdd(&rowsum[i0 + wave * 32 + mi * 16 + q * 4 + r], s);
        }

    __syncthreads();   // full drain: all csumS LDS atomics visible
    for (int k = tid; k < ntiles * 128; k += 256) {
        float v = csumS[k];
        if (v != 0.f) atomicAdd(&rowsum[jt0 * 128 + k], v);
    }
    #undef STAGE_HALF
}

__global__ void finalize_kernel(const float* __restrict__ rowsum, float* __restrict__ out) {
    __shared__ float red[4];
    int gid = blockIdx.x * 256 + threadIdx.x;
    float lg = __logf(rowsum[gid]);
    #pragma unroll
    for (int off = 1; off < 64; off <<= 1)
        lg += __shfl_xor(lg, off);
    const int wv = threadIdx.x >> 6, ln = threadIdx.x & 63;
    if (ln == 0) red[wv] = lg;
    __syncthreads();
    if (threadIdx.x == 0)
        atomicAdd(out, (red[0] + red[1] + red[2] + red[3]) * (1.0f / (float)NROWS));
}

extern "C" void kernel_launch(void* const* d_in, const int* in_sizes, int n_in,
                              void* d_out, int out_size, void* d_ws, size_t ws_size,
                              hipStream_t stream) {
    const float* x = (const float*)d_in[0];
    float* out = (float*)d_out;

    float* rowsum = (float*)d_ws;                                                 // 48 KB
    unsigned short* xb = (unsigned short*)((char*)d_ws + NROWS * sizeof(float));  // 3 MB bf16

    convert_kernel<<<dim3((NROWS * DDIM) / (4 * 256)), dim3(256), 0, stream>>>(x, xb, rowsum, out);
    gemm_exp_rowsum<<<dim3(NBLK), dim3(256), 0, stream>>>(xb, rowsum);
    finalize_kernel<<<dim3(NROWS / 256), dim3(256), 0, stream>>>(rowsum, out);
}

// Round 8
// 98.215 us; speedup vs baseline: 1.0779x; 1.0603x over previous
//
#include <hip/hip_runtime.h>
#include <hip/hip_bf16.h>

#define NROWS 12288
#define DDIM  128
#define NT    96      // 12288/128 tiles per dimension
#define CHUNK 12      // j-tiles per block
#define NBLK  432     // sum_{n=1..96} ceil(n/12) = 12*(1+..+8) = 432 -> single round at 2 blk/CU

typedef __bf16 bf16x8 __attribute__((ext_vector_type(8)));
typedef float  f32x4  __attribute__((ext_vector_type(4)));

__device__ __forceinline__ unsigned short f2bf(float f) {
    union { float f; unsigned u; } a; a.f = f;
    unsigned r = a.u + 0x7fffu + ((a.u >> 16) & 1u);   // RNE to bf16
    return (unsigned short)(r >> 16);
}

// Convert f32 -> bf16 AND permute into fragment-major layout:
// for 16-row block rb, k-chunk ks (16B units c = ks*4+q), lane l = m16 + 16q:
//   xbT ushort offset ((rb*4 + ks)*64 + l) * 8  holds row rb*16+m16, bytes [c*16, c*16+16)
// so every MFMA fragment load is ONE fully-coalesced 1KB global_load_dwordx4.
__global__ void convert_kernel(const float* __restrict__ x, unsigned short* __restrict__ xbT,
                               float* __restrict__ rowsum, float* __restrict__ out) {
    int gid = blockIdx.x * 256 + threadIdx.x;    // 196608 threads, one 16B chunk each
    int e = gid << 3;
    float4 v0 = *(const float4*)(x + e);
    float4 v1 = *(const float4*)(x + e + 4);
    uint4 o;
    o.x = (unsigned)f2bf(v0.x) | ((unsigned)f2bf(v0.y) << 16);
    o.y = (unsigned)f2bf(v0.z) | ((unsigned)f2bf(v0.w) << 16);
    o.z = (unsigned)f2bf(v1.x) | ((unsigned)f2bf(v1.y) << 16);
    o.w = (unsigned)f2bf(v1.z) | ((unsigned)f2bf(v1.w) << 16);
    int r = gid >> 4;          // row  (= e/128)
    int c = gid & 15;          // 16B chunk within row
    size_t off = ((size_t)((r >> 4) * 4 + (c >> 2)) * 64 + (c & 3) * 16 + (r & 15)) * 8;
    *(uint4*)(xbT + off) = o;
    if (gid < NROWS) rowsum[gid] = 0.f;
    if (gid == 0) out[0] = 0.f;
}

// Barrier-free GEMM+exp+rowsum: no LDS staging, no DMA, no per-tile barriers.
// Block = 4 waves over a 128-row band; wave (wr,wc) owns the 64x64 sub-tile
// (rows wr*64, cols wc*64) of each 128x128 tile in the strip. A fragments are
// register-resident across the strip; B fragments are coalesced 1KB loads from
// the L2-resident fragment-major xbT. Waves are fully independent -> they
// de-phase and the compiler pipelines loads under MFMA/exp freely.
__global__ __launch_bounds__(256, 2) void gemm_exp_rowsum(
    const unsigned short* __restrict__ xbT, float* __restrict__ rowsum)
{
    __shared__ float csumS[CHUNK * 128];         // 6 KB col partials

    const int tid = threadIdx.x;

    // decode blockIdx -> (band bi, chunk start jt0)
    int rem = blockIdx.x, bi = 0;
    for (;;) {
        int nch = (NT - bi + CHUNK - 1) / CHUNK;
        if (rem < nch) break;
        rem -= nch; ++bi;
    }
    const int jt0 = bi + rem * CHUNK;
    const int ntiles = min(CHUNK, NT - jt0);
    const int i0 = bi * 128;

    for (int k = tid; k < CHUNK * 128; k += 256) csumS[k] = 0.f;

    const int wave = tid >> 6, lane = tid & 63;
    const int m16 = lane & 15, q = lane >> 4;
    const int wr = wave >> 1, wc = wave & 1;     // 2x2 waves, 64x64 sub-tiles

    // A fragments: row-blocks arb = bi*8 + wr*4 + mi, all ks. 64 VGPR, strip-resident.
    bf16x8 af[4][4];
    #pragma unroll
    for (int mi = 0; mi < 4; ++mi) {
        int arb = bi * 8 + wr * 4 + mi;
        #pragma unroll
        for (int ks = 0; ks < 4; ++ks)
            af[mi][ks] = *(const bf16x8*)(xbT + ((size_t)(arb * 4 + ks) * 64 + lane) * 8);
    }
    __syncthreads();   // csumS zeroed (only barrier before the end)

    // exp(s/T) == exp2(s * invT*log2e)
    const float SCALE = 20.609929155556625f;     // (1/0.07) * log2(e)

    f32x4 rp4[4];
    #pragma unroll
    for (int mi = 0; mi < 4; ++mi) rp4[mi] = (f32x4){0.f, 0.f, 0.f, 0.f};

    for (int t = 0; t < ntiles; ++t) {
        const int jt = jt0 + t;

        // 16 coalesced 1KB fragment loads for this wave's 64 cols x K=128
        const unsigned short* bbase = xbT + (size_t)((jt * 8 + wc * 4) * 4) * 64 * 8;
        bf16x8 bfr[4][4];                        // [ks][ni]
        #pragma unroll
        for (int ks = 0; ks < 4; ++ks)
            #pragma unroll
            for (int ni = 0; ni < 4; ++ni)
                bfr[ks][ni] = *(const bf16x8*)(bbase + ((size_t)(ni * 4 + ks) * 64 + lane) * 8);

        f32x4 acc[4][4] = {};
        #pragma unroll
        for (int ks = 0; ks < 4; ++ks)
            #pragma unroll
            for (int mi = 0; mi < 4; ++mi)
                #pragma unroll
                for (int ni = 0; ni < 4; ++ni)
                    acc[mi][ni] = __builtin_amdgcn_mfma_f32_16x16x32_bf16(
                        af[mi][ks], bfr[ks][ni], acc[mi][ni], 0, 0, 0);

        // C/D layout: col = m16, row = q*4 + r  [verified, absmax=0]
        f32x4 cp4[4];
        #pragma unroll
        for (int ni = 0; ni < 4; ++ni) cp4[ni] = (f32x4){0.f, 0.f, 0.f, 0.f};

        #pragma unroll
        for (int mi = 0; mi < 4; ++mi)
            #pragma unroll
            for (int ni = 0; ni < 4; ++ni) {
                f32x4 sv = acc[mi][ni] * SCALE;
                f32x4 ev;
                ev[0] = __builtin_amdgcn_exp2f(sv[0]);
                ev[1] = __builtin_amdgcn_exp2f(sv[1]);
                ev[2] = __builtin_amdgcn_exp2f(sv[2]);
                ev[3] = __builtin_amdgcn_exp2f(sv[3]);
                rp4[mi] += ev;                   // row partials (register, whole strip)
                cp4[ni] += ev;                   // col partials (this tile)
            }

        if (jt != bi) {                          // diagonal tile: rows only, no double count
            #pragma unroll
            for (int ni = 0; ni < 4; ++ni) {
                float s = (cp4[ni][0] + cp4[ni][1]) + (cp4[ni][2] + cp4[ni][3]);
                s += __shfl_xor(s, 16);
                s += __shfl_xor(s, 32);
                if (q == 0) atomicAdd(&csumS[t * 128 + wc * 64 + ni * 16 + m16], s);
            }
        }
    }

    // row totals: row = i0 + wr*64 + mi*16 + q*4 + r; reduce over the 16 m16-lanes
    #pragma unroll
    for (int mi = 0; mi < 4; ++mi)
        #pragma unroll
        for (int r = 0; r < 4; ++r) {
            float s = rp4[mi][r];
            s += __shfl_xor(s, 1);
            s += __shfl_xor(s, 2);
            s += __shfl_xor(s, 4);
            s += __shfl_xor(s, 8);
            if (m16 == 0) atomicAdd(&rowsum[i0 + wr * 64 + mi * 16 + q * 4 + r], s);
        }

    __syncthreads();   // all csumS LDS atomics visible
    for (int k = tid; k < ntiles * 128; k += 256) {
        float v = csumS[k];
        if (v != 0.f) atomicAdd(&rowsum[jt0 * 128 + k], v);
    }
}

__global__ void finalize_kernel(const float* __restrict__ rowsum, float* __restrict__ out) {
    __shared__ float red[4];
    int gid = blockIdx.x * 256 + threadIdx.x;
    float lg = __logf(rowsum[gid]);
    #pragma unroll
    for (int off = 1; off < 64; off <<= 1)
        lg += __shfl_xor(lg, off);
    const int wv = threadIdx.x >> 6, ln = threadIdx.x & 63;
    if (ln == 0) red[wv] = lg;
    __syncthreads();
    if (threadIdx.x == 0)
        atomicAdd(out, (red[0] + red[1] + red[2] + red[3]) * (1.0f / (float)NROWS));
}

extern "C" void kernel_launch(void* const* d_in, const int* in_sizes, int n_in,
                              void* d_out, int out_size, void* d_ws, size_t ws_size,
                              hipStream_t stream) {
    const float* x = (const float*)d_in[0];
    float* out = (float*)d_out;

    float* rowsum = (float*)d_ws;                                                  // 48 KB
    unsigned short* xbT = (unsigned short*)((char*)d_ws + NROWS * sizeof(float));  // 3 MB bf16, frag-major

    convert_kernel<<<dim3((NROWS * DDIM) / (8 * 256)), dim3(256), 0, stream>>>(x, xbT, rowsum, out);
    gemm_exp_rowsum<<<dim3(NBLK), dim3(256), 0, stream>>>(xbT, rowsum);
    finalize_kernel<<<dim3(NROWS / 256), dim3(256), 0, stream>>>(rowsum, out);
}